// Round 8
// baseline (189.666 us; speedup 1.0000x reference)
//
#include <hip/hip_runtime.h>
#include <hip/hip_bf16.h>
#include <math.h>

#define BB 64
#define TT 500
#define DD 64
#define SS 50
#define CH 20
#define NCH (TT / CH)   // 25
#define NW 8            // waves per k2 block (8-way s-split)

__device__ __forceinline__ float sigmoidf_(float x) { return 1.0f / (1.0f + __expf(-x)); }

// v_readlane_b32: VALU->SGPR broadcast (~2cy). __shfl would emit
// ds_bpermute_b32 (LDS pipe) -- measured 630cy/step in round 5.
__device__ __forceinline__ float rdlane(float v, int l) {
    return __int_as_float(__builtin_amdgcn_readlane(__float_as_int(v), l));
}

// Memory-clobber scheduling fence: loads issued above cannot sink below.
#define PIN() asm volatile("" ::: "memory")

// ---------------------------------------------------------------------------
// Kernel 1: tables. blocks [0,ncon): wTab[c][50] = softmax(embed_key[c]·Mk^T)
//   blocks [ncon,ncon+nv): eaTab[x][d] = {sigmoid(ev@We+be), tanh(ev@Wa+ba)}
// ---------------------------------------------------------------------------
__global__ __launch_bounds__(64) void k1_tables(
    const float* __restrict__ embed_key,
    const float* __restrict__ embed_value,
    const float* __restrict__ Mk,
    const float* __restrict__ We, const float* __restrict__ be,
    const float* __restrict__ Wa, const float* __restrict__ ba,
    int ncon, int nv,
    float* __restrict__ wTab, float* __restrict__ eaTab)
{
    const int lane = threadIdx.x;
    if ((int)blockIdx.x < ncon) {
        const int c = blockIdx.x;
        __shared__ float mkS[SS][DD + 1];
        __shared__ float kS[DD];
        kS[lane] = embed_key[c * DD + lane];
        for (int s = 0; s < SS; ++s)
            mkS[s][lane] = Mk[s * DD + lane];
        __syncthreads();

        float sc = -1e30f;
        if (lane < SS) {
            float acc = 0.f;
            #pragma unroll
            for (int dd = 0; dd < DD; ++dd)
                acc = fmaf(kS[dd], mkS[lane][dd], acc);
            sc = acc;
        }
        float m = sc;
        #pragma unroll
        for (int off = 32; off >= 1; off >>= 1)
            m = fmaxf(m, __shfl_xor(m, off));
        float ex = (lane < SS) ? __expf(sc - m) : 0.f;
        float ssum = ex;
        #pragma unroll
        for (int off = 32; off >= 1; off >>= 1)
            ssum += __shfl_xor(ssum, off);
        if (lane < SS)
            wTab[c * SS + lane] = ex / ssum;
    } else {
        const int x = blockIdx.x - ncon;
        __shared__ float vS[DD];
        vS[lane] = embed_value[x * DD + lane];
        __syncthreads();
        float acc_e = be[lane];
        float acc_a = ba[lane];
        #pragma unroll
        for (int i = 0; i < DD; ++i) {
            const float vi = vS[i];
            acc_e = fmaf(vi, We[i * DD + lane], acc_e);
            acc_a = fmaf(vi, Wa[i * DD + lane], acc_a);
        }
        float2 ea;
        ea.x = sigmoidf_(acc_e);
        ea.y = tanhf(acc_a);
        *(float2*)&eaTab[((size_t)x * DD + lane) * 2] = ea;
    }
}

// ---------------------------------------------------------------------------
// Kernel 2: scan. grid = BB blocks (one per b), 512 threads = 8 waves.
// Wave sg owns s in [st,en) (6-7 states, zero-padded w to uniform 7) in regs.
// 2 waves/SIMD -> stalls of one wave hidden by the other. Per step per wave:
// 7 readlane + 21 FMA + 1 ds_write (imm-offset). Chunk A/B register
// ping-pong with PIN fences; per-chunk LDS reduce of r over the 8 waves ->
// single rOut plane (8.2MB writes vs 32MB; no atomics).
// ---------------------------------------------------------------------------
#define GW(WD, KK, T0) {                                                     \
    const int tt_ = (KK) * 8 + (lane >> 3);                                  \
    const int j_ = lane & 7;                                                 \
    const int s_ = st + j_;                                                  \
    WD = (tt_ < CH && s_ < en) ? wTab[cL[(T0) + tt_] * SS + s_] : 0.f; }

#define GLOAD(P, T0)                                                         \
    GW(w##P##0, 0, T0) GW(w##P##1, 1, T0) GW(w##P##2, 2, T0)                 \
    _Pragma("unroll")                                                        \
    for (int tt = 0; tt < CH; ++tt) {                                        \
        const int xx_ = xL[(T0) + tt];                                       \
        ea##P[tt] = *(const float2*)&eaTab[((size_t)xx_ * DD + lane) * 2]; }

#define UPD(WW, JJ) {                                                        \
    const float mv_ = Mv[JJ];                                                \
    if ((JJ) & 1) r1 = fmaf(WW, mv_, r1); else r0 = fmaf(WW, mv_, r0);       \
    Mv[JJ] = fmaf(-(WW), fmaf(e_, mv_, -a_), mv_); }

#define STEP(P, WREG, tc) {                                                  \
    const float e_ = ea##P[tc].x, a_ = ea##P[tc].y;                          \
    const float x0_ = rdlane(WREG, ((tc) & 7) * 8 + 0);                      \
    const float x1_ = rdlane(WREG, ((tc) & 7) * 8 + 1);                      \
    const float x2_ = rdlane(WREG, ((tc) & 7) * 8 + 2);                      \
    const float x3_ = rdlane(WREG, ((tc) & 7) * 8 + 3);                      \
    const float x4_ = rdlane(WREG, ((tc) & 7) * 8 + 4);                      \
    const float x5_ = rdlane(WREG, ((tc) & 7) * 8 + 5);                      \
    const float x6_ = rdlane(WREG, ((tc) & 7) * 8 + 6);                      \
    float r0 = 0.f, r1 = 0.f;                                                \
    UPD(x0_, 0) UPD(x1_, 1) UPD(x2_, 2) UPD(x3_, 3)                          \
    UPD(x4_, 4) UPD(x5_, 5) UPD(x6_, 6)                                      \
    parts[tc][sg][lane] = r0 + r1; }

#define CCOMP(P)                                                             \
    STEP(P, w##P##0, 0)  STEP(P, w##P##0, 1)  STEP(P, w##P##0, 2)            \
    STEP(P, w##P##0, 3)  STEP(P, w##P##0, 4)  STEP(P, w##P##0, 5)            \
    STEP(P, w##P##0, 6)  STEP(P, w##P##0, 7)                                 \
    STEP(P, w##P##1, 8)  STEP(P, w##P##1, 9)  STEP(P, w##P##1, 10)           \
    STEP(P, w##P##1, 11) STEP(P, w##P##1, 12) STEP(P, w##P##1, 13)           \
    STEP(P, w##P##1, 14) STEP(P, w##P##1, 15)                                \
    STEP(P, w##P##2, 16) STEP(P, w##P##2, 17) STEP(P, w##P##2, 18)           \
    STEP(P, w##P##2, 19)

#define RED(T0) {                                                            \
    __syncthreads();                                                         \
    _Pragma("unroll")                                                        \
    for (int o = tid; o < CH * DD; o += 512) {                               \
        const int tc2 = o >> 6, d2 = o & 63;                                 \
        float s_ = parts[tc2][0][d2] + parts[tc2][1][d2]                     \
                 + parts[tc2][2][d2] + parts[tc2][3][d2]                     \
                 + parts[tc2][4][d2] + parts[tc2][5][d2]                     \
                 + parts[tc2][6][d2] + parts[tc2][7][d2];                    \
        rOut[((size_t)b * TT + (T0) + tc2) * DD + d2] = s_;                  \
    }                                                                        \
    __syncthreads(); }

__global__ __launch_bounds__(512) void k2_scan(
    const int* __restrict__ cseq,
    const int* __restrict__ corr,
    const int* __restrict__ ncp,
    const float* __restrict__ wTab,
    const float* __restrict__ eaTab,
    const float* __restrict__ Mv0,
    float* __restrict__ rOut)
{
    const int b = blockIdx.x;
    const int tid = threadIdx.x;
    const int lane = tid & 63;
    const int sg = tid >> 6;          // wave id = s-group
    const int nc = ncp[0];

    __shared__ int xL[TT];
    __shared__ int cL[TT];
    __shared__ float parts[CH][NW][DD];   // 40KB

    for (int i = tid; i < TT; i += 512) {
        const int c = cseq[b * TT + i];
        cL[i] = c;
        xL[i] = c + nc * corr[b * TT + i];
    }
    __syncthreads();

    // s ranges: sg0:0-6  sg1:7-13  sg2:14-19 ... sg7:44-49 (7,7,6,6,6,6,6,6)
    const int st = (sg < 2) ? sg * 7 : 14 + (sg - 2) * 6;
    const int en = st + ((sg < 2) ? 7 : 6);

    float Mv[7];
    #pragma unroll
    for (int j = 0; j < 7; ++j) {
        const int s = st + j;
        Mv[j] = (s < en) ? Mv0[s * DD + lane] : 0.f;
    }

    float2 eaA[CH], eaB[CH];
    float wA0, wA1, wA2, wB0, wB1, wB2;

    GLOAD(A, 0)
    PIN();

    for (int ch = 0; ch < NCH - 1; ch += 2) {
        const int T0a = ch * CH;
        const int T0b = T0a + CH;
        const int T0c = T0a + 2 * CH;        // <= (NCH-1)*CH, always valid
        GLOAD(B, T0b)
        PIN();
        CCOMP(A)
        RED(T0a)
        GLOAD(A, T0c)
        PIN();
        CCOMP(B)
        RED(T0b)
    }
    CCOMP(A)
    RED((NCH - 1) * CH)                      // tail chunk 24
}

// ---------------------------------------------------------------------------
// Kernel 3: output head as a tiled [64bt x 64j] fp32 GEMM with Wf in LDS.
// 500 blocks x 256 threads; thread (ty,tx) computes a 4bt x 4j register tile.
// ---------------------------------------------------------------------------
__global__ __launch_bounds__(256) void k3_output(
    const int* __restrict__ cseq,
    const float* __restrict__ embed_key,
    const float* __restrict__ rOut,
    const float* __restrict__ Wf, const float* __restrict__ bf,
    const float* __restrict__ Wab, const float* __restrict__ bab,
    const float* __restrict__ Wd, const float* __restrict__ bd,
    float* __restrict__ out)
{
    const int tid = threadIdx.x;
    const int tx = tid & 15, ty = tid >> 4;
    const int bt0 = blockIdx.x * 64;

    __shared__ float __align__(16) wfS[128][64];
    __shared__ float __align__(16) catT[128][68];
    __shared__ float qS[64];
    __shared__ float redS[64][17];

    #pragma unroll
    for (int k = 0; k < 8; ++k) {
        const int idx = tid + k * 256;
        ((float4*)wfS)[idx] = ((const float4*)Wf)[idx];
    }

    {
        const int d = tid & 63;
        const int g = tid >> 6;
        const float wd = Wd[d];
        #pragma unroll
        for (int m = 0; m < 16; ++m) {
            const int btl = g + 4 * m;
            const int bt = bt0 + btl;
            const int c = cseq[bt];
            const float r  = rOut[(size_t)bt * DD + d];
            const float kv = embed_key[c * DD + d];
            catT[d][btl] = r;
            catT[64 + d][btl] = kv;
            float q = kv * wd;
            #pragma unroll
            for (int off = 32; off >= 1; off >>= 1)
                q += __shfl_xor(q, off);
            if (d == 0) qS[btl] = q;
        }
    }
    __syncthreads();

    float acc[4][4] = {{0.f}};
    #pragma unroll 8
    for (int i = 0; i < 128; ++i) {
        const float4 wf = *(const float4*)&wfS[i][tx * 4];
        const float4 ct = *(const float4*)&catT[i][ty * 4];
        acc[0][0] = fmaf(ct.x, wf.x, acc[0][0]);
        acc[0][1] = fmaf(ct.x, wf.y, acc[0][1]);
        acc[0][2] = fmaf(ct.x, wf.z, acc[0][2]);
        acc[0][3] = fmaf(ct.x, wf.w, acc[0][3]);
        acc[1][0] = fmaf(ct.y, wf.x, acc[1][0]);
        acc[1][1] = fmaf(ct.y, wf.y, acc[1][1]);
        acc[1][2] = fmaf(ct.y, wf.z, acc[1][2]);
        acc[1][3] = fmaf(ct.y, wf.w, acc[1][3]);
        acc[2][0] = fmaf(ct.z, wf.x, acc[2][0]);
        acc[2][1] = fmaf(ct.z, wf.y, acc[2][1]);
        acc[2][2] = fmaf(ct.z, wf.z, acc[2][2]);
        acc[2][3] = fmaf(ct.z, wf.w, acc[2][3]);
        acc[3][0] = fmaf(ct.w, wf.x, acc[3][0]);
        acc[3][1] = fmaf(ct.w, wf.y, acc[3][1]);
        acc[3][2] = fmaf(ct.w, wf.z, acc[3][2]);
        acc[3][3] = fmaf(ct.w, wf.w, acc[3][3]);
    }

    #pragma unroll
    for (int ii = 0; ii < 4; ++ii) {
        float p = 0.f;
        #pragma unroll
        for (int jj = 0; jj < 4; ++jj) {
            const int j = tx * 4 + jj;
            const float f = tanhf(acc[ii][jj] + bf[j]);
            p = fmaf(f, Wab[j], p);
        }
        redS[ty * 4 + ii][tx] = p;
    }
    __syncthreads();

    if (tid < 64) {
        const int btl = tid;
        float s = 0.f;
        #pragma unroll
        for (int t2 = 0; t2 < 16; ++t2)
            s += redS[btl][t2];
        const float stu  = tanhf(s + bab[0]);
        const float diff = tanhf(qS[btl] + bd[0]);
        out[bt0 + btl] = sigmoidf_(3.0f * stu - diff);
    }
}

// ---------------------------------------------------------------------------
extern "C" void kernel_launch(void* const* d_in, const int* in_sizes, int n_in,
                              void* d_out, int out_size, void* d_ws, size_t ws_size,
                              hipStream_t stream)
{
    const int*   concept_seq = (const int*)  d_in[0];
    const int*   correct_seq = (const int*)  d_in[1];
    const int*   num_concept = (const int*)  d_in[2];
    const float* embed_key   = (const float*)d_in[3];
    const float* embed_value = (const float*)d_in[4];
    const float* Mk          = (const float*)d_in[5];
    const float* Mv0         = (const float*)d_in[6];
    const float* Wf          = (const float*)d_in[7];
    const float* bf          = (const float*)d_in[8];
    const float* We          = (const float*)d_in[9];
    const float* be          = (const float*)d_in[10];
    const float* Wa          = (const float*)d_in[11];
    const float* ba          = (const float*)d_in[12];
    const float* Wab         = (const float*)d_in[13];
    const float* bab         = (const float*)d_in[14];
    const float* Wd          = (const float*)d_in[15];
    const float* bd          = (const float*)d_in[16];
    float* out = (float*)d_out;

    const int NCON = in_sizes[3] / DD;   // 1024
    const int NV   = in_sizes[4] / DD;   // 2048

    float* wTab  = (float*)d_ws;                       // NCON*SS
    float* eaTab = wTab + (size_t)NCON * SS;           // NV*DD*2
    float* rOut  = eaTab + (size_t)NV * DD * 2;        // BB*TT*DD (single plane)

    k1_tables<<<NCON + NV, 64, 0, stream>>>(
        embed_key, embed_value, Mk, We, be, Wa, ba,
        NCON, NV, wTab, eaTab);

    k2_scan<<<BB, 512, 0, stream>>>(
        concept_seq, correct_seq, num_concept,
        wTab, eaTab, Mv0, rOut);

    k3_output<<<(BB * TT) / 64, 256, 0, stream>>>(
        concept_seq, embed_key, rOut,
        Wf, bf, Wab, bab, Wd, bd, out);
}

// Round 9
// 170.688 us; speedup vs baseline: 1.1112x; 1.1112x over previous
//
#include <hip/hip_runtime.h>
#include <hip/hip_bf16.h>
#include <math.h>

#define BB 64
#define TT 500
#define DD 64
#define SS 50
#define CH 20
#define NCH (TT / CH)   // 25

typedef float v2f __attribute__((ext_vector_type(2)));

__device__ __forceinline__ float sigmoidf_(float x) { return 1.0f / (1.0f + __expf(-x)); }

// Compiler barrier: global loads issued above cannot sink below (round 6/7
// lesson: without it the chunk prefetch sinks to just-before-use).
#define PIN() asm volatile("" ::: "memory")

// ---------------------------------------------------------------------------
// Kernel 1: tables. blocks [0,ncon): wTab[c][50] = softmax(embed_key[c]·Mk^T)
//   blocks [ncon,ncon+nv): eaTab[x][d] = {sigmoid(ev@We+be), tanh(ev@Wa+ba)}
// ---------------------------------------------------------------------------
__global__ __launch_bounds__(64) void k1_tables(
    const float* __restrict__ embed_key,
    const float* __restrict__ embed_value,
    const float* __restrict__ Mk,
    const float* __restrict__ We, const float* __restrict__ be,
    const float* __restrict__ Wa, const float* __restrict__ ba,
    int ncon, int nv,
    float* __restrict__ wTab, float* __restrict__ eaTab)
{
    const int lane = threadIdx.x;
    if ((int)blockIdx.x < ncon) {
        const int c = blockIdx.x;
        __shared__ float mkS[SS][DD + 1];
        __shared__ float kS[DD];
        kS[lane] = embed_key[c * DD + lane];
        for (int s = 0; s < SS; ++s)
            mkS[s][lane] = Mk[s * DD + lane];
        __syncthreads();

        float sc = -1e30f;
        if (lane < SS) {
            float acc = 0.f;
            #pragma unroll
            for (int dd = 0; dd < DD; ++dd)
                acc = fmaf(kS[dd], mkS[lane][dd], acc);
            sc = acc;
        }
        float m = sc;
        #pragma unroll
        for (int off = 32; off >= 1; off >>= 1)
            m = fmaxf(m, __shfl_xor(m, off));
        float ex = (lane < SS) ? __expf(sc - m) : 0.f;
        float ssum = ex;
        #pragma unroll
        for (int off = 32; off >= 1; off >>= 1)
            ssum += __shfl_xor(ssum, off);
        if (lane < SS)
            wTab[c * SS + lane] = ex / ssum;
    } else {
        const int x = blockIdx.x - ncon;
        __shared__ float vS[DD];
        vS[lane] = embed_value[x * DD + lane];
        __syncthreads();
        float acc_e = be[lane];
        float acc_a = ba[lane];
        #pragma unroll
        for (int i = 0; i < DD; ++i) {
            const float vi = vS[i];
            acc_e = fmaf(vi, We[i * DD + lane], acc_e);
            acc_a = fmaf(vi, Wa[i * DD + lane], acc_a);
        }
        float2 ea;
        ea.x = sigmoidf_(acc_e);
        ea.y = tanhf(acc_a);
        *(float2*)&eaTab[((size_t)x * DD + lane) * 2] = ea;
    }
}

// ---------------------------------------------------------------------------
// Kernel 2: scan. grid = BB*4 blocks (b, sgB), 64 threads (lane = d), ONE
// wave per block (no barriers; same-wave LDS ordering via lgkmcnt).
// Wave owns 12-13 s-states as 7 v2f pairs. Per step:
//   w: 3x ds_read_b128 + 1x ds_read_b64, uniform address -> broadcast
//   ea: 1x ds_read_b64 (lane-indexed, 2-way bank = free)
//   math: 21x v_pk_fma_f32 (s-pairs)
// Chunk pipeline (T14): issue ch+1 global loads (PIN) -> compute ch from
// LDS -> ds_write ch+1 (vmcnt drains after compute). No atomics; partials
// to per-sgB plane, k3 sums 4 planes.
// ---------------------------------------------------------------------------
#define STAGE_ISSUE(T0) {                                                    \
    _Pragma("unroll")                                                        \
    for (int kk = 0; kk < 5; ++kk) {                                         \
        const int idx_ = lane + 64 * kk;                                     \
        const int tt_ = idx_ >> 4, j_ = idx_ & 15;                           \
        const int s_ = st + j_;                                              \
        wr[kk] = (s_ < en) ? wTab[cL[(T0) + tt_] * SS + s_] : 0.f;           \
    }                                                                        \
    _Pragma("unroll")                                                        \
    for (int tt = 0; tt < CH; ++tt) {                                        \
        const int xx_ = xL[(T0) + tt];                                       \
        ear[tt] = *(const float2*)&eaTab[((size_t)xx_ * DD + lane) * 2];     \
    } }

#define STAGE_WRITE(BUF) {                                                   \
    _Pragma("unroll")                                                        \
    for (int kk = 0; kk < 5; ++kk) {                                         \
        const int idx_ = lane + 64 * kk;                                     \
        wL[BUF][idx_ >> 4][idx_ & 15] = wr[kk];                              \
    }                                                                        \
    _Pragma("unroll")                                                        \
    for (int tt = 0; tt < CH; ++tt)                                          \
        eaL[BUF][tt][lane] = ear[tt];                                        \
    }

#define PKSTEP(W2, JJ) {                                                     \
    const v2f mv_ = Mv2[JJ];                                                 \
    r2 = __builtin_elementwise_fma(W2, mv_, r2);                             \
    const v2f g_ = __builtin_elementwise_fma(e2, mv_, na2);                  \
    Mv2[JJ] = __builtin_elementwise_fma(-(W2), g_, mv_); }

__global__ __launch_bounds__(64, 1) void k2_scan(
    const int* __restrict__ cseq,
    const int* __restrict__ corr,
    const int* __restrict__ ncp,
    const float* __restrict__ wTab,
    const float* __restrict__ eaTab,
    const float* __restrict__ Mv0,
    float* __restrict__ rPart)
{
    const int b = blockIdx.x >> 2;
    const int sgB = blockIdx.x & 3;
    const int lane = threadIdx.x;
    const int nc = ncp[0];

    __shared__ int xL[TT];
    __shared__ int cL[TT];
    __shared__ float __align__(16) wL[2][CH][16];    // 2.5KB
    __shared__ float2 __align__(8) eaL[2][CH][DD];   // 20KB

    for (int i = lane; i < TT; i += 64) {
        const int c = cseq[b * TT + i];
        cL[i] = c;
        xL[i] = c + nc * corr[b * TT + i];
    }
    __syncthreads();

    const int st = (SS * sgB) >> 2;          // {0,12,25,37}
    const int en = (SS * (sgB + 1)) >> 2;    // {12,25,37,50}

    v2f Mv2[7];
    #pragma unroll
    for (int jj = 0; jj < 7; ++jj) {
        const int s0 = st + 2 * jj, s1 = s0 + 1;
        v2f m;
        m.x = (s0 < en) ? Mv0[s0 * DD + lane] : 0.f;
        m.y = (s1 < en) ? Mv0[s1 * DD + lane] : 0.f;
        Mv2[jj] = m;
    }

    float* rp = rPart + ((size_t)sgB * BB + b) * TT * DD + lane;

    float wr[5];
    float2 ear[CH];

    STAGE_ISSUE(0)
    STAGE_WRITE(0)

    for (int ch = 0; ch < NCH; ++ch) {
        const int buf = ch & 1;
        if (ch + 1 < NCH) {
            STAGE_ISSUE((ch + 1) * CH)
            PIN();
        }
        const int T0 = ch * CH;
        #pragma unroll
        for (int tc = 0; tc < CH; ++tc) {
            const float4 wq0 = *(const float4*)&wL[buf][tc][0];
            const float4 wq1 = *(const float4*)&wL[buf][tc][4];
            const float4 wq2 = *(const float4*)&wL[buf][tc][8];
            const v2f   w6_ = *(const v2f*)  &wL[buf][tc][12];
            const float2 ea = eaL[buf][tc][lane];
            const v2f e2  = {ea.x, ea.x};
            const v2f na2 = {-ea.y, -ea.y};
            const v2f w0_ = {wq0.x, wq0.y};
            const v2f w1_ = {wq0.z, wq0.w};
            const v2f w2_ = {wq1.x, wq1.y};
            const v2f w3_ = {wq1.z, wq1.w};
            const v2f w4_ = {wq2.x, wq2.y};
            const v2f w5_ = {wq2.z, wq2.w};
            v2f r2 = {0.f, 0.f};
            PKSTEP(w0_, 0) PKSTEP(w1_, 1) PKSTEP(w2_, 2) PKSTEP(w3_, 3)
            PKSTEP(w4_, 4) PKSTEP(w5_, 5) PKSTEP(w6_, 6)
            rp[(size_t)(T0 + tc) * DD] = r2.x + r2.y;
        }
        if (ch + 1 < NCH)
            STAGE_WRITE((ch + 1) & 1)   // vmcnt on issued loads drains here
    }
}

// ---------------------------------------------------------------------------
// Kernel 3: output head as a tiled [64bt x 64j] fp32 GEMM with Wf in LDS.
// 500 blocks x 256 threads; thread (ty,tx) computes a 4bt x 4j register tile.
// catT staging sums the 4 rPart planes. que_diff via a 64-thread LDS pass
// (replaces the 96-deep shfl_xor chain of rounds 4-8).
// ---------------------------------------------------------------------------
__global__ __launch_bounds__(256) void k3_output(
    const int* __restrict__ cseq,
    const float* __restrict__ embed_key,
    const float* __restrict__ rPart,
    const float* __restrict__ Wf, const float* __restrict__ bf,
    const float* __restrict__ Wab, const float* __restrict__ bab,
    const float* __restrict__ Wd, const float* __restrict__ bd,
    float* __restrict__ out)
{
    const int tid = threadIdx.x;
    const int tx = tid & 15, ty = tid >> 4;
    const int bt0 = blockIdx.x * 64;

    __shared__ float __align__(16) wfS[128][64];
    __shared__ float __align__(16) catT[128][68];
    __shared__ float qS[64];
    __shared__ float wdS[64];
    __shared__ float redS[64][17];

    #pragma unroll
    for (int k = 0; k < 8; ++k) {
        const int idx = tid + k * 256;
        ((float4*)wfS)[idx] = ((const float4*)Wf)[idx];
    }
    if (tid < 64) wdS[tid] = Wd[tid];

    {
        const int d = tid & 63;
        const int g = tid >> 6;
        #pragma unroll
        for (int m = 0; m < 16; ++m) {
            const int btl = g + 4 * m;
            const int bt = bt0 + btl;
            const int c = cseq[bt];
            const size_t o = (size_t)bt * DD + d;
            const float r = rPart[o]
                          + rPart[(size_t)1 * BB * TT * DD + o]
                          + rPart[(size_t)2 * BB * TT * DD + o]
                          + rPart[(size_t)3 * BB * TT * DD + o];
            catT[d][btl] = r;
            catT[64 + d][btl] = embed_key[c * DD + d];
        }
    }
    __syncthreads();

    // que_diff: thread btl sums catT[64+i][btl]*Wd[i] (2-way banks = free)
    if (tid < 64) {
        const int btl = tid;
        float q = 0.f;
        #pragma unroll
        for (int i = 0; i < DD; ++i)
            q = fmaf(catT[64 + i][btl], wdS[i], q);
        qS[btl] = q;
    }

    float acc[4][4] = {{0.f}};
    #pragma unroll 8
    for (int i = 0; i < 128; ++i) {
        const float4 wf = *(const float4*)&wfS[i][tx * 4];
        const float4 ct = *(const float4*)&catT[i][ty * 4];
        acc[0][0] = fmaf(ct.x, wf.x, acc[0][0]);
        acc[0][1] = fmaf(ct.x, wf.y, acc[0][1]);
        acc[0][2] = fmaf(ct.x, wf.z, acc[0][2]);
        acc[0][3] = fmaf(ct.x, wf.w, acc[0][3]);
        acc[1][0] = fmaf(ct.y, wf.x, acc[1][0]);
        acc[1][1] = fmaf(ct.y, wf.y, acc[1][1]);
        acc[1][2] = fmaf(ct.y, wf.z, acc[1][2]);
        acc[1][3] = fmaf(ct.y, wf.w, acc[1][3]);
        acc[2][0] = fmaf(ct.z, wf.x, acc[2][0]);
        acc[2][1] = fmaf(ct.z, wf.y, acc[2][1]);
        acc[2][2] = fmaf(ct.z, wf.z, acc[2][2]);
        acc[2][3] = fmaf(ct.z, wf.w, acc[2][3]);
        acc[3][0] = fmaf(ct.w, wf.x, acc[3][0]);
        acc[3][1] = fmaf(ct.w, wf.y, acc[3][1]);
        acc[3][2] = fmaf(ct.w, wf.z, acc[3][2]);
        acc[3][3] = fmaf(ct.w, wf.w, acc[3][3]);
    }

    #pragma unroll
    for (int ii = 0; ii < 4; ++ii) {
        float p = 0.f;
        #pragma unroll
        for (int jj = 0; jj < 4; ++jj) {
            const int j = tx * 4 + jj;
            const float f = tanhf(acc[ii][jj] + bf[j]);
            p = fmaf(f, Wab[j], p);
        }
        redS[ty * 4 + ii][tx] = p;
    }
    __syncthreads();

    if (tid < 64) {
        const int btl = tid;
        float s = 0.f;
        #pragma unroll
        for (int t2 = 0; t2 < 16; ++t2)
            s += redS[btl][t2];
        const float stu  = tanhf(s + bab[0]);
        const float diff = tanhf(qS[btl] + bd[0]);
        out[bt0 + btl] = sigmoidf_(3.0f * stu - diff);
    }
}

// ---------------------------------------------------------------------------
extern "C" void kernel_launch(void* const* d_in, const int* in_sizes, int n_in,
                              void* d_out, int out_size, void* d_ws, size_t ws_size,
                              hipStream_t stream)
{
    const int*   concept_seq = (const int*)  d_in[0];
    const int*   correct_seq = (const int*)  d_in[1];
    const int*   num_concept = (const int*)  d_in[2];
    const float* embed_key   = (const float*)d_in[3];
    const float* embed_value = (const float*)d_in[4];
    const float* Mk          = (const float*)d_in[5];
    const float* Mv0         = (const float*)d_in[6];
    const float* Wf          = (const float*)d_in[7];
    const float* bf          = (const float*)d_in[8];
    const float* We          = (const float*)d_in[9];
    const float* be          = (const float*)d_in[10];
    const float* Wa          = (const float*)d_in[11];
    const float* ba          = (const float*)d_in[12];
    const float* Wab         = (const float*)d_in[13];
    const float* bab         = (const float*)d_in[14];
    const float* Wd          = (const float*)d_in[15];
    const float* bd          = (const float*)d_in[16];
    float* out = (float*)d_out;

    const int NCON = in_sizes[3] / DD;   // 1024
    const int NV   = in_sizes[4] / DD;   // 2048

    float* wTab  = (float*)d_ws;                       // NCON*SS
    float* eaTab = wTab + (size_t)NCON * SS;           // NV*DD*2
    float* rPart = eaTab + (size_t)NV * DD * 2;        // 4 * BB*TT*DD

    k1_tables<<<NCON + NV, 64, 0, stream>>>(
        embed_key, embed_value, Mk, We, be, Wa, ba,
        NCON, NV, wTab, eaTab);

    k2_scan<<<BB * 4, 64, 0, stream>>>(
        concept_seq, correct_seq, num_concept,
        wTab, eaTab, Mv0, rPart);

    k3_output<<<(BB * TT) / 64, 256, 0, stream>>>(
        concept_seq, embed_key, rPart,
        Wf, bf, Wab, bab, Wd, bd, out);
}

// Round 10
// 166.326 us; speedup vs baseline: 1.1403x; 1.0262x over previous
//
#include <hip/hip_runtime.h>
#include <hip/hip_bf16.h>
#include <math.h>

#define BB 64
#define TT 500
#define DD 64
#define SS 50
#define CH 20
#define NCH (TT / CH)   // 25

typedef float v2f __attribute__((ext_vector_type(2)));

__device__ __forceinline__ float sigmoidf_(float x) { return 1.0f / (1.0f + __expf(-x)); }

// Compiler barrier: memory ops above cannot sink below (rounds 6/7/9 lesson:
// without it the scheduler sinks prefetch loads to just-before-use).
#define PIN() asm volatile("" ::: "memory")

// ---------------------------------------------------------------------------
// Kernel 1: tables. blocks [0,ncon): wTab[c][50] = softmax(embed_key[c]·Mk^T)
//   blocks [ncon,ncon+nv): eaTab[x][d] = {sigmoid(ev@We+be), tanh(ev@Wa+ba)}
// ---------------------------------------------------------------------------
__global__ __launch_bounds__(64) void k1_tables(
    const float* __restrict__ embed_key,
    const float* __restrict__ embed_value,
    const float* __restrict__ Mk,
    const float* __restrict__ We, const float* __restrict__ be,
    const float* __restrict__ Wa, const float* __restrict__ ba,
    int ncon, int nv,
    float* __restrict__ wTab, float* __restrict__ eaTab)
{
    const int lane = threadIdx.x;
    if ((int)blockIdx.x < ncon) {
        const int c = blockIdx.x;
        __shared__ float mkS[SS][DD + 1];
        __shared__ float kS[DD];
        kS[lane] = embed_key[c * DD + lane];
        for (int s = 0; s < SS; ++s)
            mkS[s][lane] = Mk[s * DD + lane];
        __syncthreads();

        float sc = -1e30f;
        if (lane < SS) {
            float acc = 0.f;
            #pragma unroll
            for (int dd = 0; dd < DD; ++dd)
                acc = fmaf(kS[dd], mkS[lane][dd], acc);
            sc = acc;
        }
        float m = sc;
        #pragma unroll
        for (int off = 32; off >= 1; off >>= 1)
            m = fmaxf(m, __shfl_xor(m, off));
        float ex = (lane < SS) ? __expf(sc - m) : 0.f;
        float ssum = ex;
        #pragma unroll
        for (int off = 32; off >= 1; off >>= 1)
            ssum += __shfl_xor(ssum, off);
        if (lane < SS)
            wTab[c * SS + lane] = ex / ssum;
    } else {
        const int x = blockIdx.x - ncon;
        __shared__ float vS[DD];
        vS[lane] = embed_value[x * DD + lane];
        __syncthreads();
        float acc_e = be[lane];
        float acc_a = ba[lane];
        #pragma unroll
        for (int i = 0; i < DD; ++i) {
            const float vi = vS[i];
            acc_e = fmaf(vi, We[i * DD + lane], acc_e);
            acc_a = fmaf(vi, Wa[i * DD + lane], acc_a);
        }
        float2 ea;
        ea.x = sigmoidf_(acc_e);
        ea.y = tanhf(acc_a);
        *(float2*)&eaTab[((size_t)x * DD + lane) * 2] = ea;
    }
}

// ---------------------------------------------------------------------------
// Kernel 2: scan. grid = BB*4 blocks (b, sgB), 64 threads (lane = d), ONE
// wave per block. Wave owns 12-13 s-states as 7 v2f pairs.
// THREE-SET REGISTER ROTATION over the LDS chunk buffers: at step t, the
// DS reads for step t+2 are issued (and PINned in place) into set (t+2)%3,
// then step t's math runs from set t%3 -> every ds_read has ~2 steps
// (~110cy) of independent math before use. Chunk pipeline (T14): issue
// ch+1 global gathers -> compute ch (pipelined) -> write ch+1 to LDS.
// ---------------------------------------------------------------------------
#define STAGE_ISSUE(T0) {                                                    \
    _Pragma("unroll")                                                        \
    for (int kk = 0; kk < 5; ++kk) {                                         \
        const int idx_ = lane + 64 * kk;                                     \
        const int tt_ = idx_ >> 4, j_ = idx_ & 15;                           \
        const int s_ = st + j_;                                              \
        wr[kk] = (s_ < en) ? wTab[cL[(T0) + tt_] * SS + s_] : 0.f;           \
    }                                                                        \
    _Pragma("unroll")                                                        \
    for (int tt = 0; tt < CH; ++tt) {                                        \
        const int xx_ = xL[(T0) + tt];                                       \
        ear[tt] = *(const float2*)&eaTab[((size_t)xx_ * DD + lane) * 2];     \
    } }

#define STAGE_WRITE(BUF) {                                                   \
    _Pragma("unroll")                                                        \
    for (int kk = 0; kk < 5; ++kk) {                                         \
        const int idx_ = lane + 64 * kk;                                     \
        wL[BUF][idx_ >> 4][idx_ & 15] = wr[kk];                              \
    }                                                                        \
    _Pragma("unroll")                                                        \
    for (int tt = 0; tt < CH; ++tt)                                          \
        eaL[BUF][tt][lane] = ear[tt];                                        \
    }

#define DECLSET(S) float4 wq0##S, wq1##S, wq2##S; v2f w6##S; float2 eac##S;

#define LOADSET(S, BUF, TC) {                                                \
    wq0##S = *(const float4*)&wL[BUF][TC][0];                                \
    wq1##S = *(const float4*)&wL[BUF][TC][4];                                \
    wq2##S = *(const float4*)&wL[BUF][TC][8];                                \
    w6##S  = *(const v2f*)&wL[BUF][TC][12];                                  \
    eac##S = eaL[BUF][TC][lane];                                             \
    PIN(); }

#define PKSTEP(W2, JJ) {                                                     \
    const v2f mv_ = Mv2[JJ];                                                 \
    r2 = __builtin_elementwise_fma(W2, mv_, r2);                             \
    const v2f g_ = __builtin_elementwise_fma(e2, mv_, na2);                  \
    Mv2[JJ] = __builtin_elementwise_fma(-(W2), g_, mv_); }

#define MATHSET(S, T0, TC) {                                                 \
    const v2f e2  = {eac##S.x, eac##S.x};                                    \
    const v2f na2 = {-eac##S.y, -eac##S.y};                                  \
    const v2f w0_ = {wq0##S.x, wq0##S.y};                                    \
    const v2f w1_ = {wq0##S.z, wq0##S.w};                                    \
    const v2f w2_ = {wq1##S.x, wq1##S.y};                                    \
    const v2f w3_ = {wq1##S.z, wq1##S.w};                                    \
    const v2f w4_ = {wq2##S.x, wq2##S.y};                                    \
    const v2f w5_ = {wq2##S.z, wq2##S.w};                                    \
    v2f r2 = {0.f, 0.f};                                                     \
    PKSTEP(w0_, 0) PKSTEP(w1_, 1) PKSTEP(w2_, 2) PKSTEP(w3_, 3)              \
    PKSTEP(w4_, 4) PKSTEP(w5_, 5) PKSTEP(w6##S, 6)                           \
    rp[(size_t)((T0) + (TC)) * DD] = r2.x + r2.y; }

// 20 steps; step t: load tc=t+2 into set (t+2)%3, math from set t%3
#define CHUNKBODY(BUF, T0)                                                   \
    LOADSET(2, BUF, 2)   MATHSET(0, T0, 0)                                   \
    LOADSET(0, BUF, 3)   MATHSET(1, T0, 1)                                   \
    LOADSET(1, BUF, 4)   MATHSET(2, T0, 2)                                   \
    LOADSET(2, BUF, 5)   MATHSET(0, T0, 3)                                   \
    LOADSET(0, BUF, 6)   MATHSET(1, T0, 4)                                   \
    LOADSET(1, BUF, 7)   MATHSET(2, T0, 5)                                   \
    LOADSET(2, BUF, 8)   MATHSET(0, T0, 6)                                   \
    LOADSET(0, BUF, 9)   MATHSET(1, T0, 7)                                   \
    LOADSET(1, BUF, 10)  MATHSET(2, T0, 8)                                   \
    LOADSET(2, BUF, 11)  MATHSET(0, T0, 9)                                   \
    LOADSET(0, BUF, 12)  MATHSET(1, T0, 10)                                  \
    LOADSET(1, BUF, 13)  MATHSET(2, T0, 11)                                  \
    LOADSET(2, BUF, 14)  MATHSET(0, T0, 12)                                  \
    LOADSET(0, BUF, 15)  MATHSET(1, T0, 13)                                  \
    LOADSET(1, BUF, 16)  MATHSET(2, T0, 14)                                  \
    LOADSET(2, BUF, 17)  MATHSET(0, T0, 15)                                  \
    LOADSET(0, BUF, 18)  MATHSET(1, T0, 16)                                  \
    LOADSET(1, BUF, 19)  MATHSET(2, T0, 17)                                  \
    MATHSET(0, T0, 18)                                                       \
    MATHSET(1, T0, 19)

__global__ __launch_bounds__(64, 1) void k2_scan(
    const int* __restrict__ cseq,
    const int* __restrict__ corr,
    const int* __restrict__ ncp,
    const float* __restrict__ wTab,
    const float* __restrict__ eaTab,
    const float* __restrict__ Mv0,
    float* __restrict__ rPart)
{
    const int b = blockIdx.x >> 2;
    const int sgB = blockIdx.x & 3;
    const int lane = threadIdx.x;
    const int nc = ncp[0];

    __shared__ int xL[TT];
    __shared__ int cL[TT];
    __shared__ float __align__(16) wL[2][CH][16];    // 2.5KB
    __shared__ float2 __align__(8) eaL[2][CH][DD];   // 20KB

    for (int i = lane; i < TT; i += 64) {
        const int c = cseq[b * TT + i];
        cL[i] = c;
        xL[i] = c + nc * corr[b * TT + i];
    }
    __syncthreads();

    const int st = (SS * sgB) >> 2;          // {0,12,25,37}
    const int en = (SS * (sgB + 1)) >> 2;    // {12,25,37,50}

    v2f Mv2[7];
    #pragma unroll
    for (int jj = 0; jj < 7; ++jj) {
        const int s0 = st + 2 * jj, s1 = s0 + 1;
        v2f m;
        m.x = (s0 < en) ? Mv0[s0 * DD + lane] : 0.f;
        m.y = (s1 < en) ? Mv0[s1 * DD + lane] : 0.f;
        Mv2[jj] = m;
    }

    float* rp = rPart + ((size_t)sgB * BB + b) * TT * DD + lane;

    float wr[5];
    float2 ear[CH];
    DECLSET(0) DECLSET(1) DECLSET(2)

    STAGE_ISSUE(0)
    STAGE_WRITE(0)
    LOADSET(0, 0, 0)
    LOADSET(1, 0, 1)

    for (int ch = 0; ch < NCH; ++ch) {
        const int buf = ch & 1;
        if (ch + 1 < NCH) {
            STAGE_ISSUE((ch + 1) * CH)
            PIN();
        }
        const int T0 = ch * CH;
        CHUNKBODY(buf, T0)
        if (ch + 1 < NCH) {
            STAGE_WRITE((ch + 1) & 1)       // vmcnt on gathers drains here
            const int nbuf = (ch + 1) & 1;
            LOADSET(0, nbuf, 0)             // refill pipeline prologue
            LOADSET(1, nbuf, 1)
        }
    }
}

// ---------------------------------------------------------------------------
// Kernel 3: output head as a tiled [64bt x 64j] fp32 GEMM with Wf in LDS.
// 500 blocks x 256 threads; thread (ty,tx) computes a 4bt x 4j register tile.
// catT staging sums the 4 rPart planes.
// ---------------------------------------------------------------------------
__global__ __launch_bounds__(256) void k3_output(
    const int* __restrict__ cseq,
    const float* __restrict__ embed_key,
    const float* __restrict__ rPart,
    const float* __restrict__ Wf, const float* __restrict__ bf,
    const float* __restrict__ Wab, const float* __restrict__ bab,
    const float* __restrict__ Wd, const float* __restrict__ bd,
    float* __restrict__ out)
{
    const int tid = threadIdx.x;
    const int tx = tid & 15, ty = tid >> 4;
    const int bt0 = blockIdx.x * 64;

    __shared__ float __align__(16) wfS[128][64];
    __shared__ float __align__(16) catT[128][68];
    __shared__ float qS[64];
    __shared__ float wdS[64];
    __shared__ float redS[64][17];

    #pragma unroll
    for (int k = 0; k < 8; ++k) {
        const int idx = tid + k * 256;
        ((float4*)wfS)[idx] = ((const float4*)Wf)[idx];
    }
    if (tid < 64) wdS[tid] = Wd[tid];

    {
        const int d = tid & 63;
        const int g = tid >> 6;
        #pragma unroll
        for (int m = 0; m < 16; ++m) {
            const int btl = g + 4 * m;
            const int bt = bt0 + btl;
            const int c = cseq[bt];
            const size_t o = (size_t)bt * DD + d;
            const float r = rPart[o]
                          + rPart[(size_t)1 * BB * TT * DD + o]
                          + rPart[(size_t)2 * BB * TT * DD + o]
                          + rPart[(size_t)3 * BB * TT * DD + o];
            catT[d][btl] = r;
            catT[64 + d][btl] = embed_key[c * DD + d];
        }
    }
    __syncthreads();

    if (tid < 64) {
        const int btl = tid;
        float q = 0.f;
        #pragma unroll
        for (int i = 0; i < DD; ++i)
            q = fmaf(catT[64 + i][btl], wdS[i], q);
        qS[btl] = q;
    }

    float acc[4][4] = {{0.f}};
    #pragma unroll 8
    for (int i = 0; i < 128; ++i) {
        const float4 wf = *(const float4*)&wfS[i][tx * 4];
        const float4 ct = *(const float4*)&catT[i][ty * 4];
        acc[0][0] = fmaf(ct.x, wf.x, acc[0][0]);
        acc[0][1] = fmaf(ct.x, wf.y, acc[0][1]);
        acc[0][2] = fmaf(ct.x, wf.z, acc[0][2]);
        acc[0][3] = fmaf(ct.x, wf.w, acc[0][3]);
        acc[1][0] = fmaf(ct.y, wf.x, acc[1][0]);
        acc[1][1] = fmaf(ct.y, wf.y, acc[1][1]);
        acc[1][2] = fmaf(ct.y, wf.z, acc[1][2]);
        acc[1][3] = fmaf(ct.y, wf.w, acc[1][3]);
        acc[2][0] = fmaf(ct.z, wf.x, acc[2][0]);
        acc[2][1] = fmaf(ct.z, wf.y, acc[2][1]);
        acc[2][2] = fmaf(ct.z, wf.z, acc[2][2]);
        acc[2][3] = fmaf(ct.z, wf.w, acc[2][3]);
        acc[3][0] = fmaf(ct.w, wf.x, acc[3][0]);
        acc[3][1] = fmaf(ct.w, wf.y, acc[3][1]);
        acc[3][2] = fmaf(ct.w, wf.z, acc[3][2]);
        acc[3][3] = fmaf(ct.w, wf.w, acc[3][3]);
    }

    #pragma unroll
    for (int ii = 0; ii < 4; ++ii) {
        float p = 0.f;
        #pragma unroll
        for (int jj = 0; jj < 4; ++jj) {
            const int j = tx * 4 + jj;
            const float f = tanhf(acc[ii][jj] + bf[j]);
            p = fmaf(f, Wab[j], p);
        }
        redS[ty * 4 + ii][tx] = p;
    }
    __syncthreads();

    if (tid < 64) {
        const int btl = tid;
        float s = 0.f;
        #pragma unroll
        for (int t2 = 0; t2 < 16; ++t2)
            s += redS[btl][t2];
        const float stu  = tanhf(s + bab[0]);
        const float diff = tanhf(qS[btl] + bd[0]);
        out[bt0 + btl] = sigmoidf_(3.0f * stu - diff);
    }
}

// ---------------------------------------------------------------------------
extern "C" void kernel_launch(void* const* d_in, const int* in_sizes, int n_in,
                              void* d_out, int out_size, void* d_ws, size_t ws_size,
                              hipStream_t stream)
{
    const int*   concept_seq = (const int*)  d_in[0];
    const int*   correct_seq = (const int*)  d_in[1];
    const int*   num_concept = (const int*)  d_in[2];
    const float* embed_key   = (const float*)d_in[3];
    const float* embed_value = (const float*)d_in[4];
    const float* Mk          = (const float*)d_in[5];
    const float* Mv0         = (const float*)d_in[6];
    const float* Wf          = (const float*)d_in[7];
    const float* bf          = (const float*)d_in[8];
    const float* We          = (const float*)d_in[9];
    const float* be          = (const float*)d_in[10];
    const float* Wa          = (const float*)d_in[11];
    const float* ba          = (const float*)d_in[12];
    const float* Wab         = (const float*)d_in[13];
    const float* bab         = (const float*)d_in[14];
    const float* Wd          = (const float*)d_in[15];
    const float* bd          = (const float*)d_in[16];
    float* out = (float*)d_out;

    const int NCON = in_sizes[3] / DD;   // 1024
    const int NV   = in_sizes[4] / DD;   // 2048

    float* wTab  = (float*)d_ws;                       // NCON*SS
    float* eaTab = wTab + (size_t)NCON * SS;           // NV*DD*2
    float* rPart = eaTab + (size_t)NV * DD * 2;        // 4 * BB*TT*DD

    k1_tables<<<NCON + NV, 64, 0, stream>>>(
        embed_key, embed_value, Mk, We, be, Wa, ba,
        NCON, NV, wTab, eaTab);

    k2_scan<<<BB * 4, 64, 0, stream>>>(
        concept_seq, correct_seq, num_concept,
        wTab, eaTab, Mv0, rPart);

    k3_output<<<(BB * TT) / 64, 256, 0, stream>>>(
        concept_seq, embed_key, rPart,
        Wf, bf, Wab, bab, Wd, bd, out);
}

// Round 11
// 162.717 us; speedup vs baseline: 1.1656x; 1.0222x over previous
//
#include <hip/hip_runtime.h>
#include <hip/hip_bf16.h>
#include <math.h>

#define BB 64
#define TT 500
#define DD 64
#define SS 50
#define CH 20
#define NCH (TT / CH)   // 25

typedef float v2f __attribute__((ext_vector_type(2)));

__device__ __forceinline__ float sigmoidf_(float x) { return 1.0f / (1.0f + __expf(-x)); }

// Compiler barrier: memory ops above cannot sink below (rounds 6/7/9 lesson).
#define PIN() asm volatile("" ::: "memory")

// ---------------------------------------------------------------------------
// Kernel 1: tables. blocks [0,ncon): wTab[c][50] = softmax(embed_key[c]·Mk^T)
//   blocks [ncon,ncon+nv): eaTab[x][d] = {sigmoid(ev@We+be), tanh(ev@Wa+ba)}
// ---------------------------------------------------------------------------
__global__ __launch_bounds__(64) void k1_tables(
    const float* __restrict__ embed_key,
    const float* __restrict__ embed_value,
    const float* __restrict__ Mk,
    const float* __restrict__ We, const float* __restrict__ be,
    const float* __restrict__ Wa, const float* __restrict__ ba,
    int ncon, int nv,
    float* __restrict__ wTab, float* __restrict__ eaTab)
{
    const int lane = threadIdx.x;
    if ((int)blockIdx.x < ncon) {
        const int c = blockIdx.x;
        __shared__ float mkS[SS][DD + 1];
        __shared__ float kS[DD];
        kS[lane] = embed_key[c * DD + lane];
        for (int s = 0; s < SS; ++s)
            mkS[s][lane] = Mk[s * DD + lane];
        __syncthreads();

        float sc = -1e30f;
        if (lane < SS) {
            float acc = 0.f;
            #pragma unroll
            for (int dd = 0; dd < DD; ++dd)
                acc = fmaf(kS[dd], mkS[lane][dd], acc);
            sc = acc;
        }
        float m = sc;
        #pragma unroll
        for (int off = 32; off >= 1; off >>= 1)
            m = fmaxf(m, __shfl_xor(m, off));
        float ex = (lane < SS) ? __expf(sc - m) : 0.f;
        float ssum = ex;
        #pragma unroll
        for (int off = 32; off >= 1; off >>= 1)
            ssum += __shfl_xor(ssum, off);
        if (lane < SS)
            wTab[c * SS + lane] = ex / ssum;
    } else {
        const int x = blockIdx.x - ncon;
        __shared__ float vS[DD];
        vS[lane] = embed_value[x * DD + lane];
        __syncthreads();
        float acc_e = be[lane];
        float acc_a = ba[lane];
        #pragma unroll
        for (int i = 0; i < DD; ++i) {
            const float vi = vS[i];
            acc_e = fmaf(vi, We[i * DD + lane], acc_e);
            acc_a = fmaf(vi, Wa[i * DD + lane], acc_a);
        }
        float2 ea;
        ea.x = sigmoidf_(acc_e);
        ea.y = tanhf(acc_a);
        *(float2*)&eaTab[((size_t)x * DD + lane) * 2] = ea;
    }
}

// ---------------------------------------------------------------------------
// Kernel 2: scan. grid = BB*4 blocks (b, sgB), 64 threads, ONE wave/block.
// Wave owns 12-13 s-states as 7 v2f pairs. 3-set DS register rotation
// (round 10) + CHUNK-LOCAL RESULT REGISTERS (this round): each step writes
// its r into one of 20 named regs (A/B sets alternate per chunk); a 20-store
// burst at chunk end makes stores fully async -- no per-step vmcnt WAR wait
// (r7/r9/r10 all stalled ~190cy/step on store-completion WAR).
// ---------------------------------------------------------------------------
#define STAGE_ISSUE(T0) {                                                    \
    _Pragma("unroll")                                                        \
    for (int kk = 0; kk < 5; ++kk) {                                         \
        const int idx_ = lane + 64 * kk;                                     \
        const int tt_ = idx_ >> 4, j_ = idx_ & 15;                           \
        const int s_ = st + j_;                                              \
        wr[kk] = (s_ < en) ? wTab[cL[(T0) + tt_] * SS + s_] : 0.f;           \
    }                                                                        \
    _Pragma("unroll")                                                        \
    for (int tt = 0; tt < CH; ++tt) {                                        \
        const int xx_ = xL[(T0) + tt];                                       \
        ear[tt] = *(const float2*)&eaTab[((size_t)xx_ * DD + lane) * 2];     \
    } }

#define STAGE_WRITE(BUF) {                                                   \
    _Pragma("unroll")                                                        \
    for (int kk = 0; kk < 5; ++kk) {                                         \
        const int idx_ = lane + 64 * kk;                                     \
        wL[BUF][idx_ >> 4][idx_ & 15] = wr[kk];                              \
    }                                                                        \
    _Pragma("unroll")                                                        \
    for (int tt = 0; tt < CH; ++tt)                                          \
        eaL[BUF][tt][lane] = ear[tt];                                        \
    }

#define DECLSET(S) float4 wq0##S, wq1##S, wq2##S; v2f w6##S; float2 eac##S;

#define LOADSET(S, BUF, TC) {                                                \
    wq0##S = *(const float4*)&wL[BUF][TC][0];                                \
    wq1##S = *(const float4*)&wL[BUF][TC][4];                                \
    wq2##S = *(const float4*)&wL[BUF][TC][8];                                \
    w6##S  = *(const v2f*)&wL[BUF][TC][12];                                  \
    eac##S = eaL[BUF][TC][lane];                                             \
    PIN(); }

#define PKSTEP(W2, JJ) {                                                     \
    const v2f mv_ = Mv2[JJ];                                                 \
    r2 = __builtin_elementwise_fma(W2, mv_, r2);                             \
    const v2f g_ = __builtin_elementwise_fma(e2, mv_, na2);                  \
    Mv2[JJ] = __builtin_elementwise_fma(-(W2), g_, mv_); }

#define MATHSET(S, P, TC) {                                                  \
    const v2f e2  = {eac##S.x, eac##S.x};                                    \
    const v2f na2 = {-eac##S.y, -eac##S.y};                                  \
    const v2f w0_ = {wq0##S.x, wq0##S.y};                                    \
    const v2f w1_ = {wq0##S.z, wq0##S.w};                                    \
    const v2f w2_ = {wq1##S.x, wq1##S.y};                                    \
    const v2f w3_ = {wq1##S.z, wq1##S.w};                                    \
    const v2f w4_ = {wq2##S.x, wq2##S.y};                                    \
    const v2f w5_ = {wq2##S.z, wq2##S.w};                                    \
    v2f r2 = {0.f, 0.f};                                                     \
    PKSTEP(w0_, 0) PKSTEP(w1_, 1) PKSTEP(w2_, 2) PKSTEP(w3_, 3)              \
    PKSTEP(w4_, 4) PKSTEP(w5_, 5) PKSTEP(w6##S, 6)                           \
    r##P##_##TC = r2.x + r2.y; }

// 20 steps; step t: DS-load tc=t+2 into set (t+2)%3, math from set t%3.
// Results land in chunk-local regs r<P>_0..r<P>_19.
#define CHUNKBODY(P, BUF)                                                    \
    LOADSET(2, BUF, 2)   MATHSET(0, P, 0)                                    \
    LOADSET(0, BUF, 3)   MATHSET(1, P, 1)                                    \
    LOADSET(1, BUF, 4)   MATHSET(2, P, 2)                                    \
    LOADSET(2, BUF, 5)   MATHSET(0, P, 3)                                    \
    LOADSET(0, BUF, 6)   MATHSET(1, P, 4)                                    \
    LOADSET(1, BUF, 7)   MATHSET(2, P, 5)                                    \
    LOADSET(2, BUF, 8)   MATHSET(0, P, 6)                                    \
    LOADSET(0, BUF, 9)   MATHSET(1, P, 7)                                    \
    LOADSET(1, BUF, 10)  MATHSET(2, P, 8)                                    \
    LOADSET(2, BUF, 11)  MATHSET(0, P, 9)                                    \
    LOADSET(0, BUF, 12)  MATHSET(1, P, 10)                                   \
    LOADSET(1, BUF, 13)  MATHSET(2, P, 11)                                   \
    LOADSET(2, BUF, 14)  MATHSET(0, P, 12)                                   \
    LOADSET(0, BUF, 15)  MATHSET(1, P, 13)                                   \
    LOADSET(1, BUF, 16)  MATHSET(2, P, 14)                                   \
    LOADSET(2, BUF, 17)  MATHSET(0, P, 15)                                   \
    LOADSET(0, BUF, 18)  MATHSET(1, P, 16)                                   \
    LOADSET(1, BUF, 19)  MATHSET(2, P, 17)                                   \
    MATHSET(0, P, 18)                                                        \
    MATHSET(1, P, 19)

#define DECLR(P)                                                             \
    float r##P##_0, r##P##_1, r##P##_2, r##P##_3, r##P##_4,                  \
          r##P##_5, r##P##_6, r##P##_7, r##P##_8, r##P##_9,                  \
          r##P##_10, r##P##_11, r##P##_12, r##P##_13, r##P##_14,             \
          r##P##_15, r##P##_16, r##P##_17, r##P##_18, r##P##_19;

#define STOREBURST(P, T0) {                                                  \
    float* rq_ = rp + (size_t)(T0) * DD;                                     \
    rq_[0 * DD]  = r##P##_0;   rq_[1 * DD]  = r##P##_1;                      \
    rq_[2 * DD]  = r##P##_2;   rq_[3 * DD]  = r##P##_3;                      \
    rq_[4 * DD]  = r##P##_4;   rq_[5 * DD]  = r##P##_5;                      \
    rq_[6 * DD]  = r##P##_6;   rq_[7 * DD]  = r##P##_7;                      \
    rq_[8 * DD]  = r##P##_8;   rq_[9 * DD]  = r##P##_9;                      \
    rq_[10 * DD] = r##P##_10;  rq_[11 * DD] = r##P##_11;                     \
    rq_[12 * DD] = r##P##_12;  rq_[13 * DD] = r##P##_13;                     \
    rq_[14 * DD] = r##P##_14;  rq_[15 * DD] = r##P##_15;                     \
    rq_[16 * DD] = r##P##_16;  rq_[17 * DD] = r##P##_17;                     \
    rq_[18 * DD] = r##P##_18;  rq_[19 * DD] = r##P##_19; }

__global__ __launch_bounds__(64, 1) void k2_scan(
    const int* __restrict__ cseq,
    const int* __restrict__ corr,
    const int* __restrict__ ncp,
    const float* __restrict__ wTab,
    const float* __restrict__ eaTab,
    const float* __restrict__ Mv0,
    float* __restrict__ rPart)
{
    const int b = blockIdx.x >> 2;
    const int sgB = blockIdx.x & 3;
    const int lane = threadIdx.x;
    const int nc = ncp[0];

    __shared__ int xL[TT];
    __shared__ int cL[TT];
    __shared__ float __align__(16) wL[2][CH][16];    // 2.5KB
    __shared__ float2 __align__(8) eaL[2][CH][DD];   // 20KB

    for (int i = lane; i < TT; i += 64) {
        const int c = cseq[b * TT + i];
        cL[i] = c;
        xL[i] = c + nc * corr[b * TT + i];
    }
    __syncthreads();

    const int st = (SS * sgB) >> 2;          // {0,12,25,37}
    const int en = (SS * (sgB + 1)) >> 2;    // {12,25,37,50}

    v2f Mv2[7];
    #pragma unroll
    for (int jj = 0; jj < 7; ++jj) {
        const int s0 = st + 2 * jj, s1 = s0 + 1;
        v2f m;
        m.x = (s0 < en) ? Mv0[s0 * DD + lane] : 0.f;
        m.y = (s1 < en) ? Mv0[s1 * DD + lane] : 0.f;
        Mv2[jj] = m;
    }

    float* rp = rPart + ((size_t)sgB * BB + b) * TT * DD + lane;

    float wr[5];
    float2 ear[CH];
    DECLSET(0) DECLSET(1) DECLSET(2)
    DECLR(A) DECLR(B)

    STAGE_ISSUE(0)
    STAGE_WRITE(0)
    LOADSET(0, 0, 0)
    LOADSET(1, 0, 1)

    for (int ch = 0; ch < NCH - 1; ch += 2) {
        const int T0a = ch * CH;
        const int T0b = T0a + CH;
        // ---- chunk ch (even): buf 0, result set A ----
        STAGE_ISSUE(T0b)
        PIN();
        CHUNKBODY(A, 0)
        STOREBURST(A, T0a)
        STAGE_WRITE(1)                      // vmcnt on gathers drains here
        LOADSET(0, 1, 0)
        LOADSET(1, 1, 1)
        // ---- chunk ch+1 (odd): buf 1, result set B ----
        const bool more = (T0b + CH) < TT;
        if (more) {
            STAGE_ISSUE(T0b + CH)
            PIN();
        }
        CHUNKBODY(B, 1)
        STOREBURST(B, T0b)
        if (more) {
            STAGE_WRITE(0)
            LOADSET(0, 0, 0)
            LOADSET(1, 0, 1)
        }
    }
    // ---- tail chunk 24 (even): buf 0, result set A ----
    CHUNKBODY(A, 0)
    STOREBURST(A, (NCH - 1) * CH)
}

// ---------------------------------------------------------------------------
// Kernel 3: output head as a tiled [64bt x 64j] fp32 GEMM with Wf in LDS.
// 500 blocks x 256 threads; thread (ty,tx) computes a 4bt x 4j register tile.
// catT staging sums the 4 rPart planes.
// ---------------------------------------------------------------------------
__global__ __launch_bounds__(256) void k3_output(
    const int* __restrict__ cseq,
    const float* __restrict__ embed_key,
    const float* __restrict__ rPart,
    const float* __restrict__ Wf, const float* __restrict__ bf,
    const float* __restrict__ Wab, const float* __restrict__ bab,
    const float* __restrict__ Wd, const float* __restrict__ bd,
    float* __restrict__ out)
{
    const int tid = threadIdx.x;
    const int tx = tid & 15, ty = tid >> 4;
    const int bt0 = blockIdx.x * 64;

    __shared__ float __align__(16) wfS[128][64];
    __shared__ float __align__(16) catT[128][68];
    __shared__ float qS[64];
    __shared__ float wdS[64];
    __shared__ float redS[64][17];

    #pragma unroll
    for (int k = 0; k < 8; ++k) {
        const int idx = tid + k * 256;
        ((float4*)wfS)[idx] = ((const float4*)Wf)[idx];
    }
    if (tid < 64) wdS[tid] = Wd[tid];

    {
        const int d = tid & 63;
        const int g = tid >> 6;
        #pragma unroll
        for (int m = 0; m < 16; ++m) {
            const int btl = g + 4 * m;
            const int bt = bt0 + btl;
            const int c = cseq[bt];
            const size_t o = (size_t)bt * DD + d;
            const float r = rPart[o]
                          + rPart[(size_t)1 * BB * TT * DD + o]
                          + rPart[(size_t)2 * BB * TT * DD + o]
                          + rPart[(size_t)3 * BB * TT * DD + o];
            catT[d][btl] = r;
            catT[64 + d][btl] = embed_key[c * DD + d];
        }
    }
    __syncthreads();

    if (tid < 64) {
        const int btl = tid;
        float q = 0.f;
        #pragma unroll
        for (int i = 0; i < DD; ++i)
            q = fmaf(catT[64 + i][btl], wdS[i], q);
        qS[btl] = q;
    }

    float acc[4][4] = {{0.f}};
    #pragma unroll 8
    for (int i = 0; i < 128; ++i) {
        const float4 wf = *(const float4*)&wfS[i][tx * 4];
        const float4 ct = *(const float4*)&catT[i][ty * 4];
        acc[0][0] = fmaf(ct.x, wf.x, acc[0][0]);
        acc[0][1] = fmaf(ct.x, wf.y, acc[0][1]);
        acc[0][2] = fmaf(ct.x, wf.z, acc[0][2]);
        acc[0][3] = fmaf(ct.x, wf.w, acc[0][3]);
        acc[1][0] = fmaf(ct.y, wf.x, acc[1][0]);
        acc[1][1] = fmaf(ct.y, wf.y, acc[1][1]);
        acc[1][2] = fmaf(ct.y, wf.z, acc[1][2]);
        acc[1][3] = fmaf(ct.y, wf.w, acc[1][3]);
        acc[2][0] = fmaf(ct.z, wf.x, acc[2][0]);
        acc[2][1] = fmaf(ct.z, wf.y, acc[2][1]);
        acc[2][2] = fmaf(ct.z, wf.z, acc[2][2]);
        acc[2][3] = fmaf(ct.z, wf.w, acc[2][3]);
        acc[3][0] = fmaf(ct.w, wf.x, acc[3][0]);
        acc[3][1] = fmaf(ct.w, wf.y, acc[3][1]);
        acc[3][2] = fmaf(ct.w, wf.z, acc[3][2]);
        acc[3][3] = fmaf(ct.w, wf.w, acc[3][3]);
    }

    #pragma unroll
    for (int ii = 0; ii < 4; ++ii) {
        float p = 0.f;
        #pragma unroll
        for (int jj = 0; jj < 4; ++jj) {
            const int j = tx * 4 + jj;
            const float f = tanhf(acc[ii][jj] + bf[j]);
            p = fmaf(f, Wab[j], p);
        }
        redS[ty * 4 + ii][tx] = p;
    }
    __syncthreads();

    if (tid < 64) {
        const int btl = tid;
        float s = 0.f;
        #pragma unroll
        for (int t2 = 0; t2 < 16; ++t2)
            s += redS[btl][t2];
        const float stu  = tanhf(s + bab[0]);
        const float diff = tanhf(qS[btl] + bd[0]);
        out[bt0 + btl] = sigmoidf_(3.0f * stu - diff);
    }
}

// ---------------------------------------------------------------------------
extern "C" void kernel_launch(void* const* d_in, const int* in_sizes, int n_in,
                              void* d_out, int out_size, void* d_ws, size_t ws_size,
                              hipStream_t stream)
{
    const int*   concept_seq = (const int*)  d_in[0];
    const int*   correct_seq = (const int*)  d_in[1];
    const int*   num_concept = (const int*)  d_in[2];
    const float* embed_key   = (const float*)d_in[3];
    const float* embed_value = (const float*)d_in[4];
    const float* Mk          = (const float*)d_in[5];
    const float* Mv0         = (const float*)d_in[6];
    const float* Wf          = (const float*)d_in[7];
    const float* bf          = (const float*)d_in[8];
    const float* We          = (const float*)d_in[9];
    const float* be          = (const float*)d_in[10];
    const float* Wa          = (const float*)d_in[11];
    const float* ba          = (const float*)d_in[12];
    const float* Wab         = (const float*)d_in[13];
    const float* bab         = (const float*)d_in[14];
    const float* Wd          = (const float*)d_in[15];
    const float* bd          = (const float*)d_in[16];
    float* out = (float*)d_out;

    const int NCON = in_sizes[3] / DD;   // 1024
    const int NV   = in_sizes[4] / DD;   // 2048

    float* wTab  = (float*)d_ws;                       // NCON*SS
    float* eaTab = wTab + (size_t)NCON * SS;           // NV*DD*2
    float* rPart = eaTab + (size_t)NV * DD * 2;        // 4 * BB*TT*DD

    k1_tables<<<NCON + NV, 64, 0, stream>>>(
        embed_key, embed_value, Mk, We, be, Wa, ba,
        NCON, NV, wTab, eaTab);

    k2_scan<<<BB * 4, 64, 0, stream>>>(
        concept_seq, correct_seq, num_concept,
        wTab, eaTab, Mv0, rPart);

    k3_output<<<(BB * TT) / 64, 256, 0, stream>>>(
        concept_seq, embed_key, rPart,
        Wf, bf, Wab, bab, Wd, bd, out);
}

// Round 12
// 152.564 us; speedup vs baseline: 1.2432x; 1.0665x over previous
//
#include <hip/hip_runtime.h>
#include <hip/hip_bf16.h>
#include <math.h>

#define BB 64
#define TT 500
#define DD 64
#define SS 50
#define PP 10            // chunks
#define LL 50            // steps per chunk (PP*LL == TT)

typedef float v2f __attribute__((ext_vector_type(2)));

__device__ __forceinline__ float sigmoidf_(float x) { return 1.0f / (1.0f + __expf(-x)); }

// ---------------------------------------------------------------------------
// Kernel 1: tables. blocks [0,ncon): wTab[c][50] = softmax(embed_key[c]·Mk^T)
//   blocks [ncon,ncon+nv): eaTab[x][d] = {sigmoid(ev@We+be), tanh(ev@Wa+ba)}
// ---------------------------------------------------------------------------
__global__ __launch_bounds__(64) void k1_tables(
    const float* __restrict__ embed_key,
    const float* __restrict__ embed_value,
    const float* __restrict__ Mk,
    const float* __restrict__ We, const float* __restrict__ be,
    const float* __restrict__ Wa, const float* __restrict__ ba,
    int ncon, int nv,
    float* __restrict__ wTab, float* __restrict__ eaTab)
{
    const int lane = threadIdx.x;
    if ((int)blockIdx.x < ncon) {
        const int c = blockIdx.x;
        __shared__ float mkS[SS][DD + 1];
        __shared__ float kS[DD];
        kS[lane] = embed_key[c * DD + lane];
        for (int s = 0; s < SS; ++s)
            mkS[s][lane] = Mk[s * DD + lane];
        __syncthreads();

        float sc = -1e30f;
        if (lane < SS) {
            float acc = 0.f;
            #pragma unroll
            for (int dd = 0; dd < DD; ++dd)
                acc = fmaf(kS[dd], mkS[lane][dd], acc);
            sc = acc;
        }
        float m = sc;
        #pragma unroll
        for (int off = 32; off >= 1; off >>= 1)
            m = fmaxf(m, __shfl_xor(m, off));
        float ex = (lane < SS) ? __expf(sc - m) : 0.f;
        float ssum = ex;
        #pragma unroll
        for (int off = 32; off >= 1; off >>= 1)
            ssum += __shfl_xor(ssum, off);
        if (lane < SS)
            wTab[c * SS + lane] = ex / ssum;
    } else {
        const int x = blockIdx.x - ncon;
        __shared__ float vS[DD];
        vS[lane] = embed_value[x * DD + lane];
        __syncthreads();
        float acc_e = be[lane];
        float acc_a = ba[lane];
        #pragma unroll
        for (int i = 0; i < DD; ++i) {
            const float vi = vS[i];
            acc_e = fmaf(vi, We[i * DD + lane], acc_e);
            acc_a = fmaf(vi, Wa[i * DD + lane], acc_a);
        }
        float2 ea;
        ea.x = sigmoidf_(acc_e);
        ea.y = tanhf(acc_a);
        *(float2*)&eaTab[((size_t)x * DD + lane) * 2] = ea;
    }
}

// ---------------------------------------------------------------------------
// PARALLEL SCAN over t (rounds 5-11 lesson: the 1-wave serial chain is
// latency-bound at ~250cy/step no matter how it's pipelined; so remove the
// 500-long chain). Recurrence per (b,s,d): m <- a*m + B with
// a = 1-w*e, B = w*a_t. Chunk maps compose associatively.
//   k2a: per (b,p) compose the 50-step chunk map (A,B)   [640 blocks, TLP]
//   k2b: per (b,s,d) apply 10 maps sequentially -> boundary states (into A)
//   k2c: per (b,p) replay 50 steps from boundary state, compute r
// ---------------------------------------------------------------------------

// common staging: cL/xL for this chunk + w (zero-padded 16-slices) + ea
#define SCAN_STAGE()                                                          \
    const int b = blockIdx.x / PP, p = blockIdx.x % PP;                       \
    const int tid = threadIdx.x;                                              \
    const int lane = tid & 63, sg = tid >> 6;                                 \
    const int t0g = p * LL;                                                   \
    if (tid < LL) {                                                           \
        const int c = cseq[b * TT + t0g + tid];                               \
        cL[tid] = c;                                                          \
        xL[tid] = c + ncp[0] * corr[b * TT + t0g + tid];                      \
    }                                                                         \
    __syncthreads();                                                          \
    for (int i = tid; i < LL * 64; i += 256) {                                \
        const int t = i >> 6, l = i & 63;                                     \
        const int sg_ = l >> 4, j_ = l & 15;                                  \
        const int st_ = (SS * sg_) >> 2, en_ = (SS * (sg_ + 1)) >> 2;         \
        const int s_ = st_ + j_;                                              \
        wLds[t][l] = (s_ < en_) ? wTab[cL[t] * SS + s_] : 0.f;                \
        eaLds[t][l] = *(const float2*)&eaTab[((size_t)xL[t] * DD + l) * 2];   \
    }

#define LOADW(t)                                                              \
    const float4 wv0 = *(const float4*)&wLds[t][sg * 16];                     \
    const float4 wv1 = *(const float4*)&wLds[t][sg * 16 + 4];                 \
    const float4 wv2 = *(const float4*)&wLds[t][sg * 16 + 8];                 \
    const v2f w6 = *(const v2f*)&wLds[t][sg * 16 + 12];                       \
    const v2f w[7] = {{wv0.x, wv0.y}, {wv0.z, wv0.w}, {wv1.x, wv1.y},         \
                      {wv1.z, wv1.w}, {wv2.x, wv2.y}, {wv2.z, wv2.w}, w6};

__global__ __launch_bounds__(256) void k2a_maps(
    const int* __restrict__ cseq, const int* __restrict__ corr,
    const int* __restrict__ ncp,
    const float* __restrict__ wTab, const float* __restrict__ eaTab,
    float* __restrict__ Aout, float* __restrict__ Bout)
{
    __shared__ int cL[LL], xL[LL];
    __shared__ float __align__(16) wLds[LL][64];
    __shared__ float2 __align__(8) eaLds[LL][64];

    SCAN_STAGE()
    __syncthreads();

    v2f A[7], Bc[7];
    #pragma unroll
    for (int j = 0; j < 7; ++j) { A[j] = (v2f){1.f, 1.f}; Bc[j] = (v2f){0.f, 0.f}; }

    const v2f one2 = {1.f, 1.f};
    #pragma unroll 2
    for (int t = 0; t < LL; ++t) {
        LOADW(t)
        const float2 ea = eaLds[t][lane];
        const v2f e2 = {ea.x, ea.x}, a2 = {ea.y, ea.y};
        #pragma unroll
        for (int j = 0; j < 7; ++j) {
            const v2f al = __builtin_elementwise_fma(-w[j], e2, one2); // 1-w*e
            const v2f be = w[j] * a2;                                  // w*a
            A[j]  = al * A[j];
            Bc[j] = __builtin_elementwise_fma(al, Bc[j], be);          // al*B+be
        }
    }

    // masked store (padded s-slots belong to the neighboring sg)
    const int st = (SS * sg) >> 2, en = (SS * (sg + 1)) >> 2;
    float* Ap = Aout + (size_t)blockIdx.x * SS * DD;
    float* Bp = Bout + (size_t)blockIdx.x * SS * DD;
    #pragma unroll
    for (int j = 0; j < 6; ++j) {
        const int s0 = st + 2 * j;
        Ap[(size_t)s0 * DD + lane] = A[j].x;
        Ap[(size_t)(s0 + 1) * DD + lane] = A[j].y;
        Bp[(size_t)s0 * DD + lane] = Bc[j].x;
        Bp[(size_t)(s0 + 1) * DD + lane] = Bc[j].y;
    }
    if (st + 12 < en) {
        Ap[(size_t)(st + 12) * DD + lane] = A[6].x;
        Bp[(size_t)(st + 12) * DD + lane] = Bc[6].x;
    }
}

// Boundary combine: m_{p+1} = A_p*m_p + B_p; store M_{p+1} into A[p].
__global__ __launch_bounds__(256) void k2b_combine(
    const float* __restrict__ Mv0,
    float* __restrict__ Aio, const float* __restrict__ Bin)
{
    const int gid = blockIdx.x * 256 + threadIdx.x;   // < BB*SS*DD (exact)
    const int d = gid & 63;
    const int s = (gid >> 6) % SS;
    const int b = gid / (SS * 64);
    float m = Mv0[s * DD + d];
    #pragma unroll
    for (int p = 0; p < PP; ++p) {
        const size_t o = (((size_t)(b * PP + p)) * SS + s) * DD + d;
        const float a = Aio[o], bb = Bin[o];
        m = fmaf(a, m, bb);
        Aio[o] = m;            // A[p] <- M_{p+1} (start state of chunk p+1)
    }
}

// Replay: start from boundary state, 50 steps, r via per-10-step LDS reduce.
__global__ __launch_bounds__(256) void k2c_replay(
    const int* __restrict__ cseq, const int* __restrict__ corr,
    const int* __restrict__ ncp,
    const float* __restrict__ wTab, const float* __restrict__ eaTab,
    const float* __restrict__ Mv0, const float* __restrict__ Mst,
    float* __restrict__ rOut)
{
    __shared__ int cL[LL], xL[LL];
    __shared__ float __align__(16) wLds[LL][64];
    __shared__ float2 __align__(8) eaLds[LL][64];
    __shared__ float parts[10][4][DD];

    SCAN_STAGE()

    // load starting state (masked; dead slots zeroed so 0*w stays 0, no NaN)
    const int st = (SS * sg) >> 2, en = (SS * (sg + 1)) >> 2;
    const float* msrc = (p == 0) ? Mv0
                       : (Mst + (size_t)(b * PP + p - 1) * SS * DD);
    v2f m[7];
    #pragma unroll
    for (int j = 0; j < 7; ++j) {
        const int s0 = st + 2 * j, s1 = s0 + 1;
        v2f mm = {0.f, 0.f};
        if (s0 < en) mm.x = msrc[(size_t)s0 * DD + lane];
        if (s1 < en) mm.y = msrc[(size_t)s1 * DD + lane];
        m[j] = mm;
    }
    __syncthreads();

    float* rb = rOut + ((size_t)b * TT + p * LL) * DD;
    for (int tq = 0; tq < LL / 10; ++tq) {
        #pragma unroll
        for (int u = 0; u < 10; ++u) {
            const int t = tq * 10 + u;
            LOADW(t)
            const float2 ea = eaLds[t][lane];
            const v2f e2 = {ea.x, ea.x}, na2 = {-ea.y, -ea.y};
            v2f r2 = {0.f, 0.f};
            #pragma unroll
            for (int j = 0; j < 7; ++j) {
                const v2f mv = m[j];
                r2 = __builtin_elementwise_fma(w[j], mv, r2);
                const v2f g = __builtin_elementwise_fma(e2, mv, na2); // e*m-a
                m[j] = __builtin_elementwise_fma(-w[j], g, mv);       // m-w*g
            }
            parts[u][sg][lane] = r2.x + r2.y;
        }
        __syncthreads();
        for (int o = tid; o < 10 * DD; o += 256) {
            const int u2 = o >> 6, d2 = o & 63;
            rb[(size_t)(tq * 10 + u2) * DD + d2] =
                parts[u2][0][d2] + parts[u2][1][d2]
              + parts[u2][2][d2] + parts[u2][3][d2];
        }
        __syncthreads();
    }
}

// ---------------------------------------------------------------------------
// Kernel 3: output head as a tiled [64bt x 64j] fp32 GEMM with Wf in LDS.
// 500 blocks x 256 threads; thread (ty,tx) computes a 4bt x 4j register tile.
// ---------------------------------------------------------------------------
__global__ __launch_bounds__(256) void k3_output(
    const int* __restrict__ cseq,
    const float* __restrict__ embed_key,
    const float* __restrict__ rOut,
    const float* __restrict__ Wf, const float* __restrict__ bf,
    const float* __restrict__ Wab, const float* __restrict__ bab,
    const float* __restrict__ Wd, const float* __restrict__ bd,
    float* __restrict__ out)
{
    const int tid = threadIdx.x;
    const int tx = tid & 15, ty = tid >> 4;
    const int bt0 = blockIdx.x * 64;

    __shared__ float __align__(16) wfS[128][64];
    __shared__ float __align__(16) catT[128][68];
    __shared__ float qS[64];
    __shared__ float wdS[64];
    __shared__ float redS[64][17];

    #pragma unroll
    for (int k = 0; k < 8; ++k) {
        const int idx = tid + k * 256;
        ((float4*)wfS)[idx] = ((const float4*)Wf)[idx];
    }
    if (tid < 64) wdS[tid] = Wd[tid];

    {
        const int d = tid & 63;
        const int g = tid >> 6;
        #pragma unroll
        for (int mq = 0; mq < 16; ++mq) {
            const int btl = g + 4 * mq;
            const int bt = bt0 + btl;
            const int c = cseq[bt];
            catT[d][btl] = rOut[(size_t)bt * DD + d];
            catT[64 + d][btl] = embed_key[c * DD + d];
        }
    }
    __syncthreads();

    if (tid < 64) {
        const int btl = tid;
        float q = 0.f;
        #pragma unroll
        for (int i = 0; i < DD; ++i)
            q = fmaf(catT[64 + i][btl], wdS[i], q);
        qS[btl] = q;
    }

    float acc[4][4] = {{0.f}};
    #pragma unroll 8
    for (int i = 0; i < 128; ++i) {
        const float4 wf = *(const float4*)&wfS[i][tx * 4];
        const float4 ct = *(const float4*)&catT[i][ty * 4];
        acc[0][0] = fmaf(ct.x, wf.x, acc[0][0]);
        acc[0][1] = fmaf(ct.x, wf.y, acc[0][1]);
        acc[0][2] = fmaf(ct.x, wf.z, acc[0][2]);
        acc[0][3] = fmaf(ct.x, wf.w, acc[0][3]);
        acc[1][0] = fmaf(ct.y, wf.x, acc[1][0]);
        acc[1][1] = fmaf(ct.y, wf.y, acc[1][1]);
        acc[1][2] = fmaf(ct.y, wf.z, acc[1][2]);
        acc[1][3] = fmaf(ct.y, wf.w, acc[1][3]);
        acc[2][0] = fmaf(ct.z, wf.x, acc[2][0]);
        acc[2][1] = fmaf(ct.z, wf.y, acc[2][1]);
        acc[2][2] = fmaf(ct.z, wf.z, acc[2][2]);
        acc[2][3] = fmaf(ct.z, wf.w, acc[2][3]);
        acc[3][0] = fmaf(ct.w, wf.x, acc[3][0]);
        acc[3][1] = fmaf(ct.w, wf.y, acc[3][1]);
        acc[3][2] = fmaf(ct.w, wf.z, acc[3][2]);
        acc[3][3] = fmaf(ct.w, wf.w, acc[3][3]);
    }

    #pragma unroll
    for (int ii = 0; ii < 4; ++ii) {
        float pacc = 0.f;
        #pragma unroll
        for (int jj = 0; jj < 4; ++jj) {
            const int j = tx * 4 + jj;
            const float f = tanhf(acc[ii][jj] + bf[j]);
            pacc = fmaf(f, Wab[j], pacc);
        }
        redS[ty * 4 + ii][tx] = pacc;
    }
    __syncthreads();

    if (tid < 64) {
        const int btl = tid;
        float s = 0.f;
        #pragma unroll
        for (int t2 = 0; t2 < 16; ++t2)
            s += redS[btl][t2];
        const float stu  = tanhf(s + bab[0]);
        const float diff = tanhf(qS[btl] + bd[0]);
        out[bt0 + btl] = sigmoidf_(3.0f * stu - diff);
    }
}

// ---------------------------------------------------------------------------
extern "C" void kernel_launch(void* const* d_in, const int* in_sizes, int n_in,
                              void* d_out, int out_size, void* d_ws, size_t ws_size,
                              hipStream_t stream)
{
    const int*   concept_seq = (const int*)  d_in[0];
    const int*   correct_seq = (const int*)  d_in[1];
    const int*   num_concept = (const int*)  d_in[2];
    const float* embed_key   = (const float*)d_in[3];
    const float* embed_value = (const float*)d_in[4];
    const float* Mk          = (const float*)d_in[5];
    const float* Mv0         = (const float*)d_in[6];
    const float* Wf          = (const float*)d_in[7];
    const float* bf          = (const float*)d_in[8];
    const float* We          = (const float*)d_in[9];
    const float* be          = (const float*)d_in[10];
    const float* Wa          = (const float*)d_in[11];
    const float* ba          = (const float*)d_in[12];
    const float* Wab         = (const float*)d_in[13];
    const float* bab         = (const float*)d_in[14];
    const float* Wd          = (const float*)d_in[15];
    const float* bd          = (const float*)d_in[16];
    float* out = (float*)d_out;

    const int NCON = in_sizes[3] / DD;   // 1024
    const int NV   = in_sizes[4] / DD;   // 2048

    float* wTab  = (float*)d_ws;                         // NCON*SS
    float* eaTab = wTab + (size_t)NCON * SS;             // NV*DD*2
    float* Abuf  = eaTab + (size_t)NV * DD * 2;          // BB*PP*SS*DD
    float* Bbuf  = Abuf + (size_t)BB * PP * SS * DD;     // BB*PP*SS*DD
    float* rOut  = Bbuf + (size_t)BB * PP * SS * DD;     // BB*TT*DD

    k1_tables<<<NCON + NV, 64, 0, stream>>>(
        embed_key, embed_value, Mk, We, be, Wa, ba,
        NCON, NV, wTab, eaTab);

    k2a_maps<<<BB * PP, 256, 0, stream>>>(
        concept_seq, correct_seq, num_concept,
        wTab, eaTab, Abuf, Bbuf);

    k2b_combine<<<(BB * SS * DD) / 256, 256, 0, stream>>>(
        Mv0, Abuf, Bbuf);

    k2c_replay<<<BB * PP, 256, 0, stream>>>(
        concept_seq, correct_seq, num_concept,
        wTab, eaTab, Mv0, Abuf, rOut);

    k3_output<<<(BB * TT) / 64, 256, 0, stream>>>(
        concept_seq, embed_key, rOut,
        Wf, bf, Wab, bab, Wd, bd, out);
}